// Round 1
// baseline (117.566 us; speedup 1.0000x reference)
//
#include <hip/hip_runtime.h>
#include <float.h>
#include <math.h>

#define BATCH 4
#define NPTS 4096
#define BLK 256
#define QCH 8                      // queries/thread, chamfer (R8: 4->8, halves LDS reads/pair)
#define QR 4                       // queries/thread, repulsion (R8: 2->4, halves LDS reads/pair)
#define SEG_CH 32                  // chamfer segments (128 pts)
#define TPTS_CH (NPTS / SEG_CH)    // 128
#define SEG_R 32                   // repulsion segments (128 pts)
#define TPTS_R (NPTS / SEG_R)      // 128
#define H2 (0.03f * 0.03f)
#define RADIUS_C 0.07f
#define EPS_C 1e-12f
#define T2 0.05f                   // rep d^2 cutoff: excluded contribs ~1e-25
#define NQ (BATCH * NPTS)          // 16384
#define NCH (2 * NQ)               // 32768 chamfer (type,b,q) rows

// d_ws (12 MB):
//   hdr    : float accum[2] + uint cnt + pad (16 B)  @ 0  (zeroed by blk 0)
//   minseg : float [SEG_CH][NCH]   (4 MB)            @ 16
//   top4   : float4[SEG_R][NQ]     (8 MB)            @ 16 + 4 MB
//
// R8 theory: partial was LDS-issue-bound (ds_read_b128 count = waves*iters,
// ~49K LDS cyc/CU vs ~26K VALU cyc/SIMD). QCH=8/QR=4 halves waves per unit
// work -> halves LDS traffic, VALU unchanged -> VALU-bound. Grid 1024 uniform
// interleaved blocks (4/CU, no tail). Merge was latency-bound (768 waves,
// unroll 8/4 = few outstanding strided loads): full unroll -> 32 coalesced
// loads in flight -> ~1 latency round; gate the rep sort-insert (values are
// mostly the T2 sentinel).

template <bool EXCL>
__device__ __forceinline__ void rep_loop(
    const float4* __restrict__ s, int base, const int (&q)[QR],
    const float (&nx)[QR], const float (&ny)[QR], const float (&nz)[QR],
    float (&m)[QR][4])
{
    #pragma unroll 2
    for (int j = 0; j < TPTS_R; ++j) {
        float4 t = s[j];
        float h[QR];
        #pragma unroll
        for (int r = 0; r < QR; ++r)
            h[r] = fmaf(nx[r], t.x, fmaf(ny[r], t.y, fmaf(nz[r], t.z, t.w)));
        if (EXCL) {
            #pragma unroll
            for (int r = 0; r < QR; ++r)
                h[r] = (base + j == q[r]) ? FLT_MAX : h[r];   // exclude self
        }
        bool gate = false;
        #pragma unroll
        for (int r = 0; r < QR; ++r) gate |= (h[r] < m[r][3]);
        if (__any(gate)) {                                    // wave-uniform, rare
            #pragma unroll
            for (int r = 0; r < QR; ++r) {
                float hv = h[r];
                float n0 = fminf(m[r][0], hv); float u0 = fmaxf(m[r][0], hv);
                float n1 = fminf(m[r][1], u0); float u1 = fmaxf(m[r][1], u0);
                float n2 = fminf(m[r][2], u1); float u2 = fmaxf(m[r][2], u1);
                float n3 = fminf(m[r][3], u2);
                m[r][0] = n0; m[r][1] = n1; m[r][2] = n2; m[r][3] = n3;
            }
        }
    }
}

// 1024 blocks: even bid = chamfer (qblk2 x type2 x b4 x seg32 = 512),
//              odd  bid = repulsion (qblk4 x b4 x seg32 = 512).
__global__ __launch_bounds__(BLK) void partial_kernel(
    const float* __restrict__ pred, const float* __restrict__ gt,
    float* __restrict__ minseg, float4* __restrict__ top4,
    unsigned int* __restrict__ hdr)
{
    __shared__ float4 s[TPTS_R];   // 128 x (x,y,z,|t|^2) = 2 KB

    if (blockIdx.x == 0 && threadIdx.x < 4)
        hdr[threadIdx.x] = 0u;     // zero accum[2]+cnt for merge

    const int bid   = blockIdx.x;
    const int isrep = bid & 1;
    const int id    = bid >> 1;    // [0,512)

    int type, b, qblk, seg;
    if (!isrep) {
        qblk = id & 1; type = (id >> 1) & 1; b = (id >> 2) & 3; seg = id >> 4;
    } else {
        qblk = id & 3; type = 2;             b = (id >> 2) & 3; seg = id >> 4;
    }
    const float* qbase = (type == 1) ? gt : pred;
    const float* tbase = (type == 0) ? gt : pred;

    // stage 128 targets: threads 0..63, 2 points each, |t|^2 on the fly
    if (threadIdx.x < 64) {
        const float2* g2 = (const float2*)(tbase + ((size_t)b * NPTS + seg * TPTS_R) * 3);
        float2 a = g2[3 * threadIdx.x + 0];
        float2 c = g2[3 * threadIdx.x + 1];
        float2 e = g2[3 * threadIdx.x + 2];
        float t20 = fmaf(a.x, a.x, fmaf(a.y, a.y, c.x * c.x));
        float t21 = fmaf(c.y, c.y, fmaf(e.x, e.x, e.y * e.y));
        s[2 * threadIdx.x + 0] = make_float4(a.x, a.y, c.x, t20);
        s[2 * threadIdx.x + 1] = make_float4(c.y, e.x, e.y, t21);
    }
    __syncthreads();

    if (!isrep) {
        const int q0 = qblk * (BLK * QCH) + threadIdx.x;      // qblk*2048 + tid
        float nx[QCH], ny[QCH], nz[QCH], q2[QCH], mn[QCH];
        #pragma unroll
        for (int k = 0; k < QCH; ++k) {
            const float* q = qbase + ((size_t)b * NPTS + q0 + k * BLK) * 3;
            float qx = q[0], qy = q[1], qz = q[2];
            q2[k] = fmaf(qx, qx, fmaf(qy, qy, qz * qz));
            nx[k] = -2.f * qx; ny[k] = -2.f * qy; nz[k] = -2.f * qz;
            mn[k] = FLT_MAX;
        }
        #pragma unroll 2
        for (int j = 0; j < TPTS_CH; j += 2) {
            float4 t0 = s[j], t1 = s[j + 1];
            #pragma unroll
            for (int k = 0; k < QCH; ++k) {
                float h0 = fmaf(nx[k], t0.x, fmaf(ny[k], t0.y, fmaf(nz[k], t0.z, t0.w)));
                float h1 = fmaf(nx[k], t1.x, fmaf(ny[k], t1.y, fmaf(nz[k], t1.z, t1.w)));
                mn[k] = fminf(fminf(mn[k], h0), h1);          // -> v_min3_f32
            }
        }
        float* row = minseg + (size_t)seg * NCH + (type * BATCH + b) * NPTS;
        #pragma unroll
        for (int k = 0; k < QCH; ++k)
            row[q0 + k * BLK] = mn[k] + q2[k];
    } else {
        const int qb = qblk * (BLK * QR) + threadIdx.x;       // qblk*1024 + tid
        int   q[QR];
        float nx[QR], ny[QR], nz[QR], q2[QR];
        float m[QR][4];
        #pragma unroll
        for (int r = 0; r < QR; ++r) {
            q[r] = qb + r * BLK;
            const float* qa = qbase + ((size_t)b * NPTS + q[r]) * 3;
            float qx = qa[0], qy = qa[1], qz = qa[2];
            q2[r] = fmaf(qx, qx, fmaf(qy, qy, qz * qz));
            nx[r] = -2.f * qx; ny[r] = -2.f * qy; nz[r] = -2.f * qz;
            // h-space cutoff init: h < T2 - q2  <=>  d2 < T2
            float a = T2 - q2[r];
            m[r][0] = a; m[r][1] = a; m[r][2] = a; m[r][3] = a;
        }
        const int base = seg * TPTS_R;
        // queries [qblk*1024, +1024) overlap targets [seg*128, +128) iff seg>>3==qblk
        if ((seg >> 3) == qblk)
            rep_loop<true >(s, base, q, nx, ny, nz, m);
        else
            rep_loop<false>(s, base, q, nx, ny, nz, m);

        float4* dst = top4 + (size_t)seg * NQ + b * NPTS;
        #pragma unroll
        for (int r = 0; r < QR; ++r)
            dst[q[r]] = make_float4(m[r][0] + q2[r], m[r][1] + q2[r],
                                    m[r][2] + q2[r], m[r][3] + q2[r]);
    }
}

// 192 blocks: [0,128) chamfer sum; [128,192) repulsion merge+eval.
// Last block (fenced atomic counter) finalizes both outputs.
__global__ __launch_bounds__(BLK) void merge_kernel(
    const float* __restrict__ minseg, const float4* __restrict__ top4,
    unsigned int* __restrict__ hdr, float* __restrict__ out)
{
    __shared__ float warr[BLK / 64];
    float contrib;
    int which;
    if (blockIdx.x < NCH / BLK) {
        int i = blockIdx.x * BLK + threadIdx.x;               // [0, 32768)
        float mval = FLT_MAX;
        #pragma unroll                                        // full: 32 loads in flight
        for (int sg = 0; sg < SEG_CH; ++sg)
            mval = fminf(mval, minseg[(size_t)sg * NCH + i]);
        contrib = fmaxf(mval, 0.f);                           // clamp as in reference
        which = 0;
    } else {
        int i = (blockIdx.x - NCH / BLK) * BLK + threadIdx.x; // [0, 16384)
        float m0 = FLT_MAX, m1 = FLT_MAX, m2 = FLT_MAX, m3 = FLT_MAX;
        #pragma unroll 8                                      // 8 float4 in flight
        for (int sg = 0; sg < SEG_R; ++sg) {
            float4 v = top4[(size_t)sg * NQ + i];
            const float vals[4] = {v.x, v.y, v.z, v.w};
            #pragma unroll
            for (int k = 0; k < 4; ++k) {
                float h = vals[k];
                if (h < m3) {                                 // mostly T2 sentinel -> skip
                    float n0 = fminf(m0, h);  float u0 = fmaxf(m0, h);
                    float n1 = fminf(m1, u0); float u1 = fmaxf(m1, u0);
                    float n2 = fminf(m2, u1); float u2 = fmaxf(m2, u1);
                    float n3 = fminf(m3, u2);
                    m0 = n0; m1 = n1; m2 = n2; m3 = n3;
                }
            }
        }
        contrib = 0.f;
        const float ms[4] = {m0, m1, m2, m3};
        #pragma unroll
        for (int k = 0; k < 4; ++k) {
            float d2 = fmaxf(ms[k], EPS_C);
            float d  = sqrtf(d2);
            contrib += (RADIUS_C - d) * expf(-d2 * (1.f / H2));
        }
        which = 1;
    }
    #pragma unroll
    for (int off = 32; off > 0; off >>= 1)
        contrib += __shfl_down(contrib, off, 64);
    if ((threadIdx.x & 63) == 0) warr[threadIdx.x >> 6] = contrib;
    __syncthreads();
    if (threadIdx.x == 0) {
        float bs = warr[0] + warr[1] + warr[2] + warr[3];
        float* accum = (float*)hdr;
        atomicAdd(&accum[which], bs);
        __threadfence();
        unsigned int old = atomicAdd(&hdr[2], 1u);
        if (old == 191u) {                                    // last block finalizes
            float a0 = atomicAdd(&accum[0], 0.f);             // coherent read
            float a1 = atomicAdd(&accum[1], 0.f);
            out[0] = 100.f * a0 * (1.f / NQ);
            out[1] = a1 * (1.f / (NQ * 4));
        }
    }
}

extern "C" void kernel_launch(void* const* d_in, const int* in_sizes, int n_in,
                              void* d_out, int out_size, void* d_ws, size_t ws_size,
                              hipStream_t stream)
{
    const float* pred = (const float*)d_in[0];
    const float* gt   = (const float*)d_in[1];

    unsigned int* hdr    = (unsigned int*)d_ws;
    float*        minseg = (float*)((char*)d_ws + 16);
    float4*       top4   = (float4*)((char*)d_ws + 16 + (size_t)SEG_CH * NCH * sizeof(float));

    partial_kernel<<<1024, BLK, 0, stream>>>(pred, gt, minseg, top4, hdr);
    merge_kernel<<<192, BLK, 0, stream>>>(minseg, top4, hdr, (float*)d_out);
}

// Round 2
// 110.239 us; speedup vs baseline: 1.0665x; 1.0665x over previous
//
#include <hip/hip_runtime.h>
#include <float.h>
#include <math.h>

#define BATCH 4
#define NPTS 4096
#define BLK 256
#define QCH 8                      // queries/thread, chamfer
#define QR 4                       // queries/thread, repulsion
#define SEG_CH 64                  // chamfer segments (64 pts each)
#define TPTS_CH (NPTS / SEG_CH)    // 64
#define SEG_R 64                   // repulsion segments (64 pts each)
#define TPTS_R (NPTS / SEG_R)      // 64
#define H2 (0.03f * 0.03f)
#define RADIUS_C 0.07f
#define EPS_C 1e-12f
#define T2 0.05f                   // rep d^2 cutoff: excluded contribs ~1e-25
#define NQ (BATCH * NPTS)          // 16384
#define NCH (2 * NQ)               // 32768 chamfer (type,b,q) rows

// d_ws (24 MB):
//   hdr    : float accum[2] + uint cnt + pad (16 B)  @ 0  (zeroed by blk 0)
//   minseg : float [SEG_CH][NCH]   (8 MB)            @ 16
//   top4   : float4[SEG_R][NQ]     (16 MB)           @ 16 + 8 MB
//
// R9 theory: R8 halved LDS traffic (QCH=8/QR=4, good) but halved residency
// (1024 blocks = 4/CU) and rep blocks drained early -> Occupancy 18.5%,
// VALUBusy 54%, partial 49us. Fix: 64-pt segments -> 2048 blocks, 8/CU,
// 32 waves/CU fully resident (launch_bounds(256,8) pins VGPR<=64), keeping
// the halved per-pair LDS traffic. Also: per-query __any gate in rep (fires
// ~17%/query/iter vs ~50% joint) cuts paid insert work ~3x.

template <bool EXCL>
__device__ __forceinline__ void rep_loop(
    const float4* __restrict__ s, int base, const int (&q)[QR],
    const float (&nx)[QR], const float (&ny)[QR], const float (&nz)[QR],
    float (&m)[QR][4])
{
    #pragma unroll 2
    for (int j = 0; j < TPTS_R; ++j) {
        float4 t = s[j];
        #pragma unroll
        for (int r = 0; r < QR; ++r) {
            float hv = fmaf(nx[r], t.x, fmaf(ny[r], t.y, fmaf(nz[r], t.z, t.w)));
            if (EXCL) hv = (base + j == q[r]) ? FLT_MAX : hv;   // exclude self
            if (__any(hv < m[r][3])) {                          // per-query gate, rare
                float n0 = fminf(m[r][0], hv); float u0 = fmaxf(m[r][0], hv);
                float n1 = fminf(m[r][1], u0); float u1 = fmaxf(m[r][1], u0);
                float n2 = fminf(m[r][2], u1); float u2 = fmaxf(m[r][2], u1);
                float n3 = fminf(m[r][3], u2);
                m[r][0] = n0; m[r][1] = n1; m[r][2] = n2; m[r][3] = n3;
            }
        }
    }
}

// 2048 blocks: even bid = chamfer (qblk2 x type2 x b4 x seg64 = 1024),
//              odd  bid = repulsion (qblk4 x b4 x seg64 = 1024).
__global__ __launch_bounds__(BLK, 8) void partial_kernel(
    const float* __restrict__ pred, const float* __restrict__ gt,
    float* __restrict__ minseg, float4* __restrict__ top4,
    unsigned int* __restrict__ hdr)
{
    __shared__ float4 s[TPTS_R];   // 64 x (x,y,z,|t|^2) = 1 KB

    if (blockIdx.x == 0 && threadIdx.x < 4)
        hdr[threadIdx.x] = 0u;     // zero accum[2]+cnt for merge

    const int bid   = blockIdx.x;
    const int isrep = bid & 1;
    const int id    = bid >> 1;    // [0,1024)

    int type, b, qblk, seg;
    if (!isrep) {
        qblk = id & 1; type = (id >> 1) & 1; b = (id >> 2) & 3; seg = id >> 4;
    } else {
        qblk = id & 3; type = 2;             b = (id >> 2) & 3; seg = id >> 4;
    }
    const float* qbase = (type == 1) ? gt : pred;
    const float* tbase = (type == 0) ? gt : pred;

    // stage 64 targets: threads 0..31, 2 points each, |t|^2 on the fly
    if (threadIdx.x < 32) {
        const float2* g2 = (const float2*)(tbase + ((size_t)b * NPTS + seg * TPTS_R) * 3);
        float2 a = g2[3 * threadIdx.x + 0];
        float2 c = g2[3 * threadIdx.x + 1];
        float2 e = g2[3 * threadIdx.x + 2];
        float t20 = fmaf(a.x, a.x, fmaf(a.y, a.y, c.x * c.x));
        float t21 = fmaf(c.y, c.y, fmaf(e.x, e.x, e.y * e.y));
        s[2 * threadIdx.x + 0] = make_float4(a.x, a.y, c.x, t20);
        s[2 * threadIdx.x + 1] = make_float4(c.y, e.x, e.y, t21);
    }
    __syncthreads();

    if (!isrep) {
        const int q0 = qblk * (BLK * QCH) + threadIdx.x;      // qblk*2048 + tid
        float nx[QCH], ny[QCH], nz[QCH], q2[QCH], mn[QCH];
        #pragma unroll
        for (int k = 0; k < QCH; ++k) {
            const float* q = qbase + ((size_t)b * NPTS + q0 + k * BLK) * 3;
            float qx = q[0], qy = q[1], qz = q[2];
            q2[k] = fmaf(qx, qx, fmaf(qy, qy, qz * qz));
            nx[k] = -2.f * qx; ny[k] = -2.f * qy; nz[k] = -2.f * qz;
            mn[k] = FLT_MAX;
        }
        #pragma unroll 2
        for (int j = 0; j < TPTS_CH; j += 2) {
            float4 t0 = s[j], t1 = s[j + 1];
            #pragma unroll
            for (int k = 0; k < QCH; ++k) {
                float h0 = fmaf(nx[k], t0.x, fmaf(ny[k], t0.y, fmaf(nz[k], t0.z, t0.w)));
                float h1 = fmaf(nx[k], t1.x, fmaf(ny[k], t1.y, fmaf(nz[k], t1.z, t1.w)));
                mn[k] = fminf(fminf(mn[k], h0), h1);          // -> v_min3_f32
            }
        }
        float* row = minseg + (size_t)seg * NCH + (type * BATCH + b) * NPTS;
        #pragma unroll
        for (int k = 0; k < QCH; ++k)
            row[q0 + k * BLK] = mn[k] + q2[k];
    } else {
        const int qb = qblk * (BLK * QR) + threadIdx.x;       // qblk*1024 + tid
        int   q[QR];
        float nx[QR], ny[QR], nz[QR], q2[QR];
        float m[QR][4];
        #pragma unroll
        for (int r = 0; r < QR; ++r) {
            q[r] = qb + r * BLK;
            const float* qa = qbase + ((size_t)b * NPTS + q[r]) * 3;
            float qx = qa[0], qy = qa[1], qz = qa[2];
            q2[r] = fmaf(qx, qx, fmaf(qy, qy, qz * qz));
            nx[r] = -2.f * qx; ny[r] = -2.f * qy; nz[r] = -2.f * qz;
            // h-space cutoff init: h < T2 - q2  <=>  d2 < T2
            float a = T2 - q2[r];
            m[r][0] = a; m[r][1] = a; m[r][2] = a; m[r][3] = a;
        }
        const int base = seg * TPTS_R;
        // queries [qblk*1024, +1024) overlap targets [seg*64, +64) iff seg>>4==qblk
        if ((seg >> 4) == qblk)
            rep_loop<true >(s, base, q, nx, ny, nz, m);
        else
            rep_loop<false>(s, base, q, nx, ny, nz, m);

        float4* dst = top4 + (size_t)seg * NQ + b * NPTS;
        #pragma unroll
        for (int r = 0; r < QR; ++r)
            dst[q[r]] = make_float4(m[r][0] + q2[r], m[r][1] + q2[r],
                                    m[r][2] + q2[r], m[r][3] + q2[r]);
    }
}

// 192 blocks: [0,128) chamfer sum; [128,192) repulsion merge+eval.
// Last block (fenced atomic counter) finalizes both outputs.
__global__ __launch_bounds__(BLK) void merge_kernel(
    const float* __restrict__ minseg, const float4* __restrict__ top4,
    unsigned int* __restrict__ hdr, float* __restrict__ out)
{
    __shared__ float warr[BLK / 64];
    float contrib;
    int which;
    if (blockIdx.x < NCH / BLK) {
        int i = blockIdx.x * BLK + threadIdx.x;               // [0, 32768)
        float mval = FLT_MAX;
        #pragma unroll                                        // full: 64 loads in flight
        for (int sg = 0; sg < SEG_CH; ++sg)
            mval = fminf(mval, minseg[(size_t)sg * NCH + i]);
        contrib = fmaxf(mval, 0.f);                           // clamp as in reference
        which = 0;
    } else {
        int i = (blockIdx.x - NCH / BLK) * BLK + threadIdx.x; // [0, 16384)
        float m0 = FLT_MAX, m1 = FLT_MAX, m2 = FLT_MAX, m3 = FLT_MAX;
        #pragma unroll 8                                      // 8 float4 in flight
        for (int sg = 0; sg < SEG_R; ++sg) {
            float4 v = top4[(size_t)sg * NQ + i];
            const float vals[4] = {v.x, v.y, v.z, v.w};
            #pragma unroll
            for (int k = 0; k < 4; ++k) {
                float h = vals[k];
                if (h < m3) {                                 // mostly T2 sentinel -> skip
                    float n0 = fminf(m0, h);  float u0 = fmaxf(m0, h);
                    float n1 = fminf(m1, u0); float u1 = fmaxf(m1, u0);
                    float n2 = fminf(m2, u1); float u2 = fmaxf(m2, u1);
                    float n3 = fminf(m3, u2);
                    m0 = n0; m1 = n1; m2 = n2; m3 = n3;
                }
            }
        }
        contrib = 0.f;
        const float ms[4] = {m0, m1, m2, m3};
        #pragma unroll
        for (int k = 0; k < 4; ++k) {
            float d2 = fmaxf(ms[k], EPS_C);
            float d  = sqrtf(d2);
            contrib += (RADIUS_C - d) * expf(-d2 * (1.f / H2));
        }
        which = 1;
    }
    #pragma unroll
    for (int off = 32; off > 0; off >>= 1)
        contrib += __shfl_down(contrib, off, 64);
    if ((threadIdx.x & 63) == 0) warr[threadIdx.x >> 6] = contrib;
    __syncthreads();
    if (threadIdx.x == 0) {
        float bs = warr[0] + warr[1] + warr[2] + warr[3];
        float* accum = (float*)hdr;
        atomicAdd(&accum[which], bs);
        __threadfence();
        unsigned int old = atomicAdd(&hdr[2], 1u);
        if (old == 191u) {                                    // last block finalizes
            float a0 = atomicAdd(&accum[0], 0.f);             // coherent read
            float a1 = atomicAdd(&accum[1], 0.f);
            out[0] = 100.f * a0 * (1.f / NQ);
            out[1] = a1 * (1.f / (NQ * 4));
        }
    }
}

extern "C" void kernel_launch(void* const* d_in, const int* in_sizes, int n_in,
                              void* d_out, int out_size, void* d_ws, size_t ws_size,
                              hipStream_t stream)
{
    const float* pred = (const float*)d_in[0];
    const float* gt   = (const float*)d_in[1];

    unsigned int* hdr    = (unsigned int*)d_ws;
    float*        minseg = (float*)((char*)d_ws + 16);
    float4*       top4   = (float4*)((char*)d_ws + 16 + (size_t)SEG_CH * NCH * sizeof(float));

    partial_kernel<<<2048, BLK, 0, stream>>>(pred, gt, minseg, top4, hdr);
    merge_kernel<<<192, BLK, 0, stream>>>(minseg, top4, hdr, (float*)d_out);
}